// Round 4
// baseline (1119.195 us; speedup 1.0000x reference)
//
#include <hip/hip_runtime.h>
#include <cstddef>
#include <cstdint>
#include <cmath>

// Problem constants
#define BDIM  64
#define SDIM  1024
#define DDIM  200
#define DPAD  224            // 7 x 32 k-steps, 14 x 16 n-tiles
#define CDIM  31
#define NSTACK 2
#define EPS   1e-5f
#define LN_N  204800.0f      // 1024*200 elements per batch LN plane

typedef __attribute__((ext_vector_type(8))) short short8;
typedef __attribute__((ext_vector_type(4))) short short4_t;
typedef __attribute__((ext_vector_type(4))) float f32x4;

__device__ __forceinline__ short f2bf(float f) {
    union { float f; unsigned u; } v; v.f = f;
    unsigned r = v.u + 0x7FFFu + ((v.u >> 16) & 1u);   // RNE
    return (short)(r >> 16);
}
__device__ __forceinline__ float bf2f(short s) {
    union { unsigned u; float f; } v; v.u = ((unsigned)(unsigned short)s) << 16;
    return v.f;
}

// ---------------- prep: padded bf16 transposed weights, biases, colsums --------
// Wt_x[n*224+k] = W_x[k*200+n]; WtM folds the 8 Wm row-blocks.
// csX[n] = sum_k bf2f(f2bf(W_x[k][n]))  (colsum of the bf16-rounded weights,
// used for the fused-LN correction: LN(y)@W = inv*(y@W) - inv*mean*colsum(W))
__global__ void prep_kernel(const float* __restrict__ Wp, const float* __restrict__ bp,
                            const float* __restrict__ Wm, const float* __restrict__ bm,
                            const float* __restrict__ W1, const float* __restrict__ b1,
                            const float* __restrict__ W2, const float* __restrict__ b2,
                            short* __restrict__ WtP, short* __restrict__ WtM,
                            short* __restrict__ Wt1, short* __restrict__ Wt2,
                            float* __restrict__ bpP, float* __restrict__ bmP,
                            float* __restrict__ b1P, float* __restrict__ b2P,
                            float* __restrict__ csP, float* __restrict__ cs1)
{
    int idx = blockIdx.x * 256 + threadIdx.x;
    if (idx >= DPAD * DPAD) return;
    int n = idx / DPAD, k = idx - n * DPAD;
    bool valid = (n < DDIM) && (k < DDIM);
    WtP[idx] = valid ? f2bf(Wp[(size_t)k * DDIM + n]) : 0;
    Wt1[idx] = valid ? f2bf(W1[(size_t)k * DDIM + n]) : 0;
    Wt2[idx] = valid ? f2bf(W2[(size_t)k * DDIM + n]) : 0;
    float s = 0.f;
    if (valid) {
        #pragma unroll
        for (int blk = 0; blk < 8; ++blk)
            s += Wm[(size_t)(blk * DDIM + k) * DDIM + n];
    }
    WtM[idx] = valid ? f2bf(s) : 0;
    if (idx < DPAD) {
        bpP[idx] = idx < DDIM ? bp[idx] : 0.f;
        bmP[idx] = idx < DDIM ? bm[idx] : 0.f;
        b1P[idx] = idx < DDIM ? b1[idx] : 0.f;
        b2P[idx] = idx < DDIM ? b2[idx] : 0.f;
        float sp = 0.f, s1 = 0.f;
        if (idx < DDIM) {
            for (int kk = 0; kk < DDIM; ++kk) {
                sp += bf2f(f2bf(Wp[(size_t)kk * DDIM + idx]));
                s1 += bf2f(f2bf(W1[(size_t)kk * DDIM + idx]));
            }
        }
        csP[idx] = sp;
        cs1[idx] = s1;
    }
}

// ---------------- h_bf = bf16(embed[x] + pos), zero-padded to 224 ----------------
__global__ void embed_kernel(const int* __restrict__ x, const float* __restrict__ embed,
                             const float* __restrict__ pos, short* __restrict__ h)
{
    const int row = blockIdx.x;            // b*S + s
    const int n = threadIdx.x;
    if (n >= DPAD) return;
    const int s = row & (SDIM - 1);
    const int tok = x[row];
    float v = (n < DDIM) ? embed[(size_t)tok * DDIM + n] + pos[(size_t)s * DDIM + n] : 0.f;
    h[(size_t)row * DPAD + n] = (n < DDIM) ? f2bf(v) : (short)0;
}

// ---------------- bf16 MFMA GEMM with fused LN on act (colsum trick) and res ----
// out[M,224] = LN?(act)[M,224] @ Wt^T + bias (+ LN?(res)) (+relu) (+stats)
// act-LN is post-hoc: v = inv_a*acc + bias - inv_a*mean_a*csW[n].
__global__ __launch_bounds__(256, 2)
void gemm_bf(const short* __restrict__ act, const float* __restrict__ actParts,
             const short* __restrict__ Wt, const float* __restrict__ bias,
             const float* __restrict__ csW,
             const short* __restrict__ res, const float* __restrict__ resParts,
             short* __restrict__ out, short* __restrict__ pt,
             float* __restrict__ parts, int doRelu)
{
    const int tid  = threadIdx.x;
    const int wave = tid >> 6, lane = tid & 63;
    const int lo   = lane & 15, hi = lane >> 4;
    const int m0   = blockIdx.x * 128 + wave * 32;

    f32x4 acc[2][14];
    #pragma unroll
    for (int mt = 0; mt < 2; ++mt)
        #pragma unroll
        for (int nt = 0; nt < 14; ++nt) acc[mt][nt] = (f32x4){0.f, 0.f, 0.f, 0.f};

    #pragma unroll
    for (int ks = 0; ks < 7; ++ks) {
        short8 bfrag[2];
        #pragma unroll
        for (int mt = 0; mt < 2; ++mt)
            bfrag[mt] = *(const short8*)(act + (size_t)(m0 + mt * 16 + lo) * DPAD + ks * 32 + hi * 8);
        #pragma unroll
        for (int nt = 0; nt < 14; ++nt) {
            short8 afrag = *(const short8*)(Wt + (size_t)(nt * 16 + lo) * DPAD + ks * 32 + hi * 8);
            acc[0][nt] = __builtin_amdgcn_mfma_f32_16x16x32_bf16(afrag, bfrag[0], acc[0][nt], 0, 0, 0);
            acc[1][nt] = __builtin_amdgcn_mfma_f32_16x16x32_bf16(afrag, bfrag[1], acc[1][nt], 0, 0, 0);
        }
    }

    const int bb = (blockIdx.x * 128) >> 10;     // batch (blocks never straddle)
    float inv_a = 1.f, corr = 0.f;
    if (actParts) {
        float mean = actParts[bb * 2] / LN_N;
        inv_a = rsqrtf(actParts[bb * 2 + 1] / LN_N - mean * mean + EPS);
        corr = mean * inv_a;
    }
    float mean_r = 0.f, inv_r = 1.f;
    if (resParts) {
        mean_r = resParts[bb * 2] / LN_N;
        inv_r = rsqrtf(resParts[bb * 2 + 1] / LN_N - mean_r * mean_r + EPS);
    }

    float s = 0.f, s2 = 0.f;
    #pragma unroll
    for (int mt = 0; mt < 2; ++mt) {
        const int m = m0 + mt * 16 + lo;
        #pragma unroll
        for (int nt = 0; nt < 14; ++nt) {
            const int nb = nt * 16 + hi * 4;
            float v[4];
            #pragma unroll
            for (int r = 0; r < 4; ++r) {
                v[r] = acc[mt][nt][r] * inv_a + bias[nb + r];
                if (actParts) v[r] -= corr * csW[nb + r];
            }
            if (res) {
                short4_t rv = *(const short4_t*)(res + (size_t)m * DPAD + nb);
                #pragma unroll
                for (int r = 0; r < 4; ++r) v[r] += (bf2f(rv[r]) - mean_r) * inv_r;
            }
            if (doRelu)
                #pragma unroll
                for (int r = 0; r < 4; ++r) v[r] = fmaxf(v[r], 0.f);
            #pragma unroll
            for (int r = 0; r < 4; ++r)
                if (nb + r >= DDIM) v[r] = 0.f;      // keep pads exactly zero
            if (parts)
                #pragma unroll
                for (int r = 0; r < 4; ++r) { s += v[r]; s2 = fmaf(v[r], v[r], s2); }
            short4_t o4;
            #pragma unroll
            for (int r = 0; r < 4; ++r) o4[r] = f2bf(v[r]);
            *(short4_t*)(out + (size_t)m * DPAD + nb) = o4;
            if (pt) {
                const int sloc = m & (SDIM - 1);
                #pragma unroll
                for (int r = 0; r < 4; ++r)
                    pt[((size_t)bb * DPAD + nb + r) * SDIM + sloc] = o4[r];
            }
        }
    }

    if (parts) {
        __shared__ float rs[4], rq[4];
        #pragma unroll
        for (int off = 32; off; off >>= 1) {
            s  += __shfl_down(s, off);
            s2 += __shfl_down(s2, off);
        }
        if (lane == 0) { rs[wave] = s; rq[wave] = s2; }
        __syncthreads();
        if (tid == 0) {
            atomicAdd(&parts[bb * 2],     rs[0] + rs[1] + rs[2] + rs[3]);
            atomicAdd(&parts[bb * 2 + 1], rq[0] + rq[1] + rq[2] + rq[3]);
        }
    }
}

// ---------------- fused MFMA flash attention (bf16 in/out) ----------------
// 1024 blocks x 256 thr (4 waves). QBLK=64: each wave owns 16 q-rows.
// K staged in LDS [64][232] (29.7KB -> 4-5 blocks/CU); V^T read straight from
// global pt (L2-resident, XCD-swizzled). P (bf16) aliases K after QK barrier.
// Softmax in exp2 domain: Q pre-scaled by 1/sqrt(D)*log2(e).
#define KSTRIDE 232
__global__ __launch_bounds__(256, 3)
void attn_kernel(const short* __restrict__ pbf, const short* __restrict__ pt,
                 short* __restrict__ c, float qscale)
{
    __shared__ short K_lds[64 * KSTRIDE];   // 29696 B; first 4096 shorts alias P

    // XCD chunk swizzle: batch b's 16 q-blocks land on one XCD
    const int bid = blockIdx.x;
    const int wg  = (bid & 7) * 128 + (bid >> 3);
    const int b   = wg >> 4;
    const int q0  = (wg & 15) * 64;

    const int tid  = threadIdx.x;
    const int wave = tid >> 6;
    const int lane = tid & 63;
    const int lo   = lane & 15;
    const int hi   = lane >> 4;

    const short* pb  = pbf + (size_t)b * SDIM * DPAD;
    const short* ptb = pt  + (size_t)b * DPAD * SDIM;

    // Q fragments (16 rows per wave), pre-scaled into exp2 domain
    short8 qf[7];
    #pragma unroll
    for (int ks = 0; ks < 7; ++ks) {
        short8 q = *(const short8*)(pb + (size_t)(q0 + wave * 16 + lo) * DPAD + ks * 32 + hi * 8);
        short8 qs;
        #pragma unroll
        for (int j = 0; j < 8; ++j) qs[j] = f2bf(bf2f(q[j]) * qscale);
        qf[ks] = qs;
    }

    f32x4 o[13];
    float m[4], ell[4];
    #pragma unroll
    for (int n = 0; n < 13; ++n) o[n] = (f32x4){0.f, 0.f, 0.f, 0.f};
    #pragma unroll
    for (int r = 0; r < 4; ++r) { m[r] = -1e30f; ell[r] = 0.f; }

    for (int kt = 0; kt < 16; ++kt) {
        const int k0 = kt * 64;
        __syncthreads();   // all waves done with P(alias K) from prev iter

        // stage K tile [64][224] -> K_lds (stride 232: conflict-free rows)
        for (int i = tid; i < 1792; i += 256) {
            int r  = i / 28;
            int c8 = i - r * 28;
            short8 v = *(const short8*)(pb + (size_t)(k0 + r) * DPAD + c8 * 8);
            *(short8*)(&K_lds[r * KSTRIDE + c8 * 8]) = v;
        }
        __syncthreads();

        // QK^T (scores already in log2 units via qscale)
        f32x4 sacc[4];
        #pragma unroll
        for (int t = 0; t < 4; ++t) sacc[t] = (f32x4){0.f, 0.f, 0.f, 0.f};
        __builtin_amdgcn_s_setprio(1);
        #pragma unroll
        for (int t = 0; t < 4; ++t)
            #pragma unroll
            for (int ks = 0; ks < 7; ++ks) {
                short8 kf = *(const short8*)(&K_lds[(t * 16 + lo) * KSTRIDE + ks * 32 + hi * 8]);
                sacc[t] = __builtin_amdgcn_mfma_f32_16x16x32_bf16(qf[ks], kf, sacc[t], 0, 0, 0);
            }
        __builtin_amdgcn_s_setprio(0);
        __syncthreads();   // all waves done reading K; safe to overwrite with P

        // online softmax (exp2 domain); write P into K-alias region
        {
            float mx[4], al[4], rsum[4];
            #pragma unroll
            for (int r = 0; r < 4; ++r)
                mx[r] = fmaxf(fmaxf(sacc[0][r], sacc[1][r]),
                              fmaxf(sacc[2][r], sacc[3][r]));
            #pragma unroll
            for (int off = 1; off <= 8; off <<= 1)
                #pragma unroll
                for (int r = 0; r < 4; ++r)
                    mx[r] = fmaxf(mx[r], __shfl_xor(mx[r], off));
            #pragma unroll
            for (int r = 0; r < 4; ++r) {
                float mn = fmaxf(m[r], mx[r]);
                al[r] = exp2f(m[r] - mn);
                m[r] = mn;
                ell[r] *= al[r];
            }
            #pragma unroll
            for (int t = 0; t < 4; ++t)
                #pragma unroll
                for (int r = 0; r < 4; ++r)
                    sacc[t][r] = exp2f(sacc[t][r] - m[r]);
            #pragma unroll
            for (int r = 0; r < 4; ++r)
                rsum[r] = sacc[0][r] + sacc[1][r] + sacc[2][r] + sacc[3][r];
            #pragma unroll
            for (int off = 1; off <= 8; off <<= 1)
                #pragma unroll
                for (int r = 0; r < 4; ++r)
                    rsum[r] += __shfl_xor(rsum[r], off);
            #pragma unroll
            for (int r = 0; r < 4; ++r) ell[r] += rsum[r];
            #pragma unroll
            for (int n = 0; n < 13; ++n)
                #pragma unroll
                for (int r = 0; r < 4; ++r) o[n][r] *= al[r];
            const int pbase = wave * 1024;
            #pragma unroll
            for (int t = 0; t < 4; ++t)
                #pragma unroll
                for (int r = 0; r < 4; ++r) {
                    int qrow = hi * 4 + r;
                    int e = pbase + ((qrow * 64 + t * 16 + lo) ^ ((qrow & 7) << 3));
                    K_lds[e] = f2bf(sacc[t][r]);
                }
        }

        // PV: O += P . V^T-rows, V fragments straight from global (L2)
        #pragma unroll
        for (int ks2 = 0; ks2 < 2; ++ks2) {
            const int poff = (lo * 64 + ks2 * 32 + hi * 8) ^ ((lo & 7) << 3);
            short8 pa = *(const short8*)(&K_lds[wave * 1024 + poff]);
            const short* vbase = ptb + k0 + ks2 * 32 + hi * 8;
            __builtin_amdgcn_s_setprio(1);
            #pragma unroll
            for (int n = 0; n < 13; ++n) {
                short8 vf = *(const short8*)(vbase + (size_t)(n * 16 + lo) * SDIM);
                o[n] = __builtin_amdgcn_mfma_f32_16x16x32_bf16(pa, vf, o[n], 0, 0, 0);
            }
            __builtin_amdgcn_s_setprio(0);
        }
    }

    // epilogue: O /= ell, store bf16 (+ zero pads 208..223)
    {
        float inv_l[4];
        #pragma unroll
        for (int r = 0; r < 4; ++r) inv_l[r] = 1.f / ell[r];
        #pragma unroll
        for (int n = 0; n < 13; ++n) {
            int dcol = n * 16 + lo;
            #pragma unroll
            for (int r = 0; r < 4; ++r) {
                size_t row = (size_t)b * SDIM + q0 + wave * 16 + hi * 4 + r;
                c[row * DPAD + dcol] = f2bf(o[n][r] * inv_l[r]);
            }
        }
        #pragma unroll
        for (int r = 0; r < 4; ++r) {
            size_t row = (size_t)b * SDIM + q0 + wave * 16 + hi * 4 + r;
            c[row * DPAD + 208 + lo] = 0;
        }
    }
}

// ---------------- final: normalize row S-1 only + head ----------------
__global__ void final_kernel(const short* __restrict__ y, const float* __restrict__ parts,
                             const float* __restrict__ Wd, const float* __restrict__ bd,
                             float* __restrict__ out)
{
    const int b = blockIdx.x;
    const float sum = parts[b * 2], sq = parts[b * 2 + 1];
    const float mean = sum / LN_N;
    const float inv  = rsqrtf(sq / LN_N - mean * mean + EPS);
    __shared__ float hrow[DDIM];
    const short* row = y + ((size_t)b * SDIM + SDIM - 1) * DPAD;
    for (int d = threadIdx.x; d < DDIM; d += blockDim.x)
        hrow[d] = (bf2f(row[d]) - mean) * inv;
    __syncthreads();
    if (threadIdx.x < CDIM) {
        float acc = bd[threadIdx.x];
        for (int d = 0; d < DDIM; ++d)
            acc = fmaf(hrow[d], Wd[(size_t)d * CDIM + threadIdx.x], acc);
        out[(size_t)b * CDIM + threadIdx.x] = acc;
    }
}

extern "C" void kernel_launch(void* const* d_in, const int* in_sizes, int n_in,
                              void* d_out, int out_size, void* d_ws, size_t ws_size,
                              hipStream_t stream)
{
    const int*   x     = (const int*)  d_in[0];
    const float* embed = (const float*)d_in[1];
    const float* pos   = (const float*)d_in[2];
    const float* Wp    = (const float*)d_in[3];
    const float* bp    = (const float*)d_in[4];
    const float* Wm    = (const float*)d_in[5];
    const float* bm    = (const float*)d_in[6];
    const float* W1    = (const float*)d_in[7];
    const float* b1    = (const float*)d_in[8];
    const float* W2    = (const float*)d_in[9];
    const float* b2    = (const float*)d_in[10];
    const float* Wd    = (const float*)d_in[11];
    const float* bd    = (const float*)d_in[12];
    float* out = (float*)d_out;

    const size_t HB = (size_t)BDIM * SDIM * DPAD;     // 14,680,064 bf16 elems

    short* h_bf  = (short*)d_ws;
    short* p_bf  = h_bf  + HB;
    short* pt    = p_bf  + HB;
    short* cb_bf = pt    + HB;
    short* yA    = cb_bf + HB;
    short* yB    = yA    + HB;
    short* WtP   = yB + HB;
    short* WtM   = WtP + DPAD * DPAD;
    short* Wt1   = WtM + DPAD * DPAD;
    short* Wt2   = Wt1 + DPAD * DPAD;
    float* bpP   = (float*)(Wt2 + DPAD * DPAD);
    float* bmP   = bpP + DPAD;
    float* b1P   = bmP + DPAD;
    float* b2P   = b1P + DPAD;
    float* csP   = b2P + DPAD;
    float* cs1   = csP + DPAD;
    float* parts = cs1 + DPAD;                        // 4 x 64 x 2 floats
    const size_t need = (size_t)((char*)(parts + 4 * BDIM * 2) - (char*)d_ws);
    if (ws_size < need) return;

    float* pA1 = parts;
    float* pB1 = parts + BDIM * 2;
    float* pA2 = parts + 2 * BDIM * 2;
    float* pB2 = parts + 3 * BDIM * 2;

    prep_kernel<<<dim3((DPAD * DPAD + 255) / 256), dim3(256), 0, stream>>>(
        Wp, bp, Wm, bm, W1, b1, W2, b2, WtP, WtM, Wt1, Wt2, bpP, bmP, b1P, b2P, csP, cs1);
    embed_kernel<<<dim3(BDIM * SDIM), dim3(256), 0, stream>>>(x, embed, pos, h_bf);
    hipMemsetAsync(parts, 0, 4 * BDIM * 2 * sizeof(float), stream);

    const float qscale = 1.44269504f / sqrtf((float)DDIM);

    // stack 1
    gemm_bf<<<dim3(512), dim3(256), 0, stream>>>(h_bf, nullptr, WtP, bpP, nullptr,
                                                 nullptr, nullptr, p_bf, pt, nullptr, 0);
    attn_kernel<<<dim3(1024), dim3(256), 0, stream>>>(p_bf, pt, cb_bf, qscale);
    gemm_bf<<<dim3(512), dim3(256), 0, stream>>>(cb_bf, nullptr, WtM, bmP, nullptr,
                                                 h_bf, nullptr, yA, nullptr, pA1, 0);
    gemm_bf<<<dim3(512), dim3(256), 0, stream>>>(yA, pA1, Wt1, b1P, cs1,
                                                 nullptr, nullptr, cb_bf, nullptr, nullptr, 1);
    gemm_bf<<<dim3(512), dim3(256), 0, stream>>>(cb_bf, nullptr, Wt2, b2P, nullptr,
                                                 yA, pA1, yB, nullptr, pB1, 0);
    // stack 2
    gemm_bf<<<dim3(512), dim3(256), 0, stream>>>(yB, pB1, WtP, bpP, csP,
                                                 nullptr, nullptr, p_bf, pt, nullptr, 0);
    attn_kernel<<<dim3(1024), dim3(256), 0, stream>>>(p_bf, pt, cb_bf, qscale);
    gemm_bf<<<dim3(512), dim3(256), 0, stream>>>(cb_bf, nullptr, WtM, bmP, nullptr,
                                                 yB, pB1, h_bf, nullptr, pA2, 0);
    gemm_bf<<<dim3(512), dim3(256), 0, stream>>>(h_bf, pA2, Wt1, b1P, cs1,
                                                 nullptr, nullptr, cb_bf, nullptr, nullptr, 1);
    gemm_bf<<<dim3(512), dim3(256), 0, stream>>>(cb_bf, nullptr, Wt2, b2P, nullptr,
                                                 h_bf, pA2, yA, nullptr, pB2, 0);
    final_kernel<<<dim3(BDIM), dim3(64), 0, stream>>>(yA, pB2, Wd, bd, out);
}